// Round 9
// baseline (201.854 us; speedup 1.0000x reference)
//
#include <hip/hip_runtime.h>

#define N_NODES 50000
#define N_EDGES 600000
#define N_GRAPHS 128
#define DIM 128
#define NLAYERS 3
#define NOUT 10
#define ELLW 48      // max degree slots (deg~Binom(600k,1/50k), P(>=48)~1e-21; clamped)
#define LSTRIDE 136  // LDS row stride in bf16 elems (272B = 17*16B: aligned, 2-way max)

typedef unsigned short u16;
typedef __attribute__((ext_vector_type(8))) short bf16x8;
typedef __attribute__((ext_vector_type(4))) float f32x4;

__device__ __forceinline__ float bf2f(u16 v) {
    unsigned u = ((unsigned)v) << 16;
    return __builtin_bit_cast(float, u);
}
__device__ __forceinline__ u16 f2bf(float f) {  // round-to-nearest-even
    unsigned u = __builtin_bit_cast(unsigned, f);
    u = u + 0x7fffu + ((u >> 16) & 1u);
    return (u16)(u >> 16);
}

// ---------------------------------------------------------------------------
// tiny: zero deg + pooled (must precede prep_all's fill_ell atomics)
__global__ void zero_small(int* __restrict__ deg, float* __restrict__ pooled) {
    int i = blockIdx.x * blockDim.x + threadIdx.x;
    if (i < N_NODES) deg[i] = 0;
    if (i < N_GRAPHS * DIM) pooled[i] = 0.f;
}

// merged prep: ELL build + x->bf16 + W pre-swizzle (independent work items)
__global__ void prep_all(int* __restrict__ deg, int* __restrict__ ell,
                         const int* __restrict__ srcs, const int* __restrict__ dsts,
                         u16* __restrict__ xb, const float* __restrict__ x,
                         u16* __restrict__ Wswz,
                         const float* __restrict__ convW1, const float* __restrict__ convW2) {
    int i = blockIdx.x * blockDim.x + threadIdx.x;
    if (i < N_EDGES) {
        int d = dsts[i];
        int slot = atomicAdd(&deg[d], 1);
        if (slot < ELLW) ell[(size_t)d * ELLW + slot] = srcs[i];
    }
    if (i < 6 * 16384) {
        int j = i & 7, lane = (i >> 3) & 63, cb = (i >> 9) & 7, kc = (i >> 12) & 3, w = i >> 14;
        int k = kc * 32 + ((lane >> 4) << 3) + j;
        int c = (cb << 4) + (lane & 15);
        const float* W = (w < 3) ? (convW1 + (size_t)w * 16384) : (convW2 + (size_t)(w - 3) * 16384);
        Wswz[i] = f2bf(W[k * DIM + c]);
    }
    if (i < N_NODES * DIM / 4) {
        float4 v = ((const float4*)x)[i];
        ushort4 o;
        o.x = f2bf(v.x); o.y = f2bf(v.y); o.z = f2bf(v.z); o.w = f2bf(v.w);
        ((ushort4*)xb)[i] = o;
    }
}

// ---------------------------------------------------------------------------
// Fused GIN layer: out = relu(MLP2(relu(BN(MLP1(x + ELL-gather(x))))))
// 256 threads = 4 waves; tile 16 rows. Each wave gathers 4 rows (unroll-8
// neighbor batches), then computes 2 col-blocks of both GEMMs (8+8 MFMA).
// 8.7 KB LDS -> 8 blocks/CU = 32 waves/CU for cross-block phase overlap.
__global__ __launch_bounds__(256) void layer_fused(
    u16* __restrict__ out, const u16* __restrict__ x,
    const int* __restrict__ deg, const int* __restrict__ ell,
    const u16* __restrict__ W1f, const u16* __restrict__ W2f,
    const float* __restrict__ b1, const float* __restrict__ g1,
    const float* __restrict__ bt1, const float* __restrict__ b2) {
    __shared__ u16 A[16 * LSTRIDE];  // 4352 B
    __shared__ u16 H[16 * LSTRIDE];  // 4352 B
    const int tid = threadIdx.x;
    const int wv = tid >> 6;
    const int lane = tid & 63;
    const int row0 = blockIdx.x * 16;

    // ---- phase 1: gather (wave wv -> rows wv*4..wv*4+3) ----
    const size_t coff = (size_t)lane * 2;
#pragma unroll
    for (int i = 0; i < 4; ++i) {
        const int r = (wv << 2) + i;
        const int grow = row0 + r;
        float ax = 0.f, ay = 0.f;
        if (grow < N_NODES) {
            ushort2 self = *(const ushort2*)(x + (size_t)grow * DIM + coff);
            ax = bf2f(self.x); ay = bf2f(self.y);
            const int len = min(deg[grow], ELLW);
            const int* ep = ell + (size_t)grow * ELLW;
            int j = 0;
            for (; j + 8 <= len; j += 8) {
                int s[8];
#pragma unroll
                for (int t = 0; t < 8; ++t) s[t] = ep[j + t];
                float px = 0.f, py = 0.f;
#pragma unroll
                for (int t = 0; t < 8; ++t) {
                    ushort2 v = *(const ushort2*)(x + (size_t)s[t] * DIM + coff);
                    px += bf2f(v.x);
                    py += bf2f(v.y);
                }
                ax += px; ay += py;
            }
            for (; j < len; ++j) {
                int s = ep[j];
                ushort2 v = *(const ushort2*)(x + (size_t)s * DIM + coff);
                ax += bf2f(v.x);
                ay += bf2f(v.y);
            }
        }
        ushort2 o; o.x = f2bf(ax); o.y = f2bf(ay);
        *(ushort2*)&A[r * LSTRIDE + lane * 2] = o;
    }
    __syncthreads();

    // ---- MFMA setup: wave wv owns col-blocks {2wv, 2wv+1} ----
    const float inv = rsqrtf(1.f + 1e-5f);
    const int col0 = lane & 15;
    const int rbl = (lane >> 4) << 2;  // C/D local row base
    const int fragoff = (lane & 15) * LSTRIDE + ((lane >> 4) << 3);

    // ---- phase 2: GEMM1 + BN + ReLU -> H ----
    {
        f32x4 acc[2];
        acc[0] = (f32x4){0.f, 0.f, 0.f, 0.f};
        acc[1] = (f32x4){0.f, 0.f, 0.f, 0.f};
#pragma unroll
        for (int kc = 0; kc < 4; ++kc) {
            bf16x8 a = *(const bf16x8*)&A[fragoff + kc * 32];
#pragma unroll
            for (int m = 0; m < 2; ++m) {
                const int cb = (wv << 1) + m;
                bf16x8 bb = *(const bf16x8*)(W1f + ((((kc << 3) + cb) << 6 | lane) << 3));
                acc[m] = __builtin_amdgcn_mfma_f32_16x16x32_bf16(a, bb, acc[m], 0, 0, 0);
            }
        }
#pragma unroll
        for (int m = 0; m < 2; ++m) {
            const int c = (((wv << 1) + m) << 4) + col0;
            const float bias = b1[c];
            const float sg = inv * g1[c];
            const float st = bt1[c];
#pragma unroll
            for (int q = 0; q < 4; ++q) {
                float v = (acc[m][q] + bias) * sg + st;
                H[(rbl + q) * LSTRIDE + c] = f2bf(fmaxf(v, 0.f));
            }
        }
    }
    __syncthreads();

    // ---- phase 3: GEMM2 + bias + ReLU -> A (dead; reuse as staging) ----
    {
        f32x4 acc[2];
        acc[0] = (f32x4){0.f, 0.f, 0.f, 0.f};
        acc[1] = (f32x4){0.f, 0.f, 0.f, 0.f};
#pragma unroll
        for (int kc = 0; kc < 4; ++kc) {
            bf16x8 a = *(const bf16x8*)&H[fragoff + kc * 32];
#pragma unroll
            for (int m = 0; m < 2; ++m) {
                const int cb = (wv << 1) + m;
                bf16x8 bb = *(const bf16x8*)(W2f + ((((kc << 3) + cb) << 6 | lane) << 3));
                acc[m] = __builtin_amdgcn_mfma_f32_16x16x32_bf16(a, bb, acc[m], 0, 0, 0);
            }
        }
#pragma unroll
        for (int m = 0; m < 2; ++m) {
            const int c = (((wv << 1) + m) << 4) + col0;
            const float bias = b2[c];
#pragma unroll
            for (int q = 0; q < 4; ++q) {
                float v = acc[m][q] + bias;
                A[(rbl + q) * LSTRIDE + c] = f2bf(fmaxf(v, 0.f));
            }
        }
    }
    __syncthreads();

    // ---- phase 4: coalesced copy-out (256 thr x 16B = full 16x128 tile) ----
    {
        const int r = tid >> 4;       // 0..15
        const int seg = tid & 15;     // 16B column segment
        const int grow = row0 + r;
        uint4 v = *(const uint4*)&A[r * LSTRIDE + seg * 8];
        if (grow < N_NODES) *(uint4*)(out + (size_t)grow * DIM + seg * 8) = v;
    }
}

// ---------------------------------------------------------------------------
// pool stage 1: one wave per 16-node chunk; batch sorted -> few flushes.
__global__ __launch_bounds__(256) void pool_partial(float* __restrict__ pooled,
                                                    const u16* __restrict__ x,
                                                    const int* __restrict__ batch) {
    const int chunk = (blockIdx.x * 256 + threadIdx.x) >> 6;
    const int lane = threadIdx.x & 63;
    const int beg = chunk * 16;
    if (beg >= N_NODES) return;
    const int end = min(beg + 16, N_NODES);
    const size_t coff = (size_t)lane * 2;

    float ax = 0.f, ay = 0.f;
    int curg = batch[beg];
    for (int n = beg; n < end; ++n) {
        int g = batch[n];
        if (g != curg) {
            atomicAdd(&pooled[(size_t)curg * DIM + coff], ax);
            atomicAdd(&pooled[(size_t)curg * DIM + coff + 1], ay);
            ax = 0.f; ay = 0.f; curg = g;
        }
        ushort2 v = *(const ushort2*)(x + (size_t)n * DIM + coff);
        ax += bf2f(v.x);
        ay += bf2f(v.y);
    }
    atomicAdd(&pooled[(size_t)curg * DIM + coff], ax);
    atomicAdd(&pooled[(size_t)curg * DIM + coff + 1], ay);
}

// pool stage 2: final MLP per graph
__global__ __launch_bounds__(128) void tail_mlp(float* __restrict__ out,
                                                const float* __restrict__ pooled,
                                                const float* __restrict__ mW1,
                                                const float* __restrict__ mb1,
                                                const float* __restrict__ mg,
                                                const float* __restrict__ mbt,
                                                const float* __restrict__ mW2,
                                                const float* __restrict__ mb2) {
    const int g = blockIdx.x;
    const int c = threadIdx.x;
    __shared__ float pl[DIM];
    __shared__ float hd[DIM];
    pl[c] = pooled[(size_t)g * DIM + c];
    __syncthreads();

    float s = 0.f;
#pragma unroll 4
    for (int k = 0; k < DIM; ++k) s += pl[k] * mW1[k * DIM + c];
    const float inv = rsqrtf(1.f + 1e-5f);
    s = (s + mb1[c]) * (inv * mg[c]) + mbt[c];
    hd[c] = fmaxf(s, 0.f);
    __syncthreads();

    if (c < NOUT) {
        float o = 0.f;
#pragma unroll 4
        for (int k = 0; k < DIM; ++k) o += hd[k] * mW2[k * NOUT + c];
        out[g * NOUT + c] = o + mb2[c];
    }
}

// ---------------------------------------------------------------------------
extern "C" void kernel_launch(void* const* d_in, const int* in_sizes, int n_in,
                              void* d_out, int out_size, void* d_ws, size_t ws_size,
                              hipStream_t stream) {
    const float* x      = (const float*)d_in[0];
    const int*   ei     = (const int*)d_in[1];
    const int*   batch  = (const int*)d_in[2];
    const float* convW1 = (const float*)d_in[3];
    const float* convb1 = (const float*)d_in[4];
    const float* convg  = (const float*)d_in[5];
    const float* convbt = (const float*)d_in[6];
    const float* convW2 = (const float*)d_in[7];
    const float* convb2 = (const float*)d_in[8];
    const float* mW1    = (const float*)d_in[9];
    const float* mb1    = (const float*)d_in[10];
    const float* mg     = (const float*)d_in[11];
    const float* mbt    = (const float*)d_in[12];
    const float* mW2    = (const float*)d_in[13];
    const float* mb2    = (const float*)d_in[14];
    float* out = (float*)d_out;

    const int* srcs = ei;
    const int* dsts = ei + N_EDGES;

    // workspace layout
    const size_t NF = (size_t)N_NODES * DIM;
    u16* xb0  = (u16*)d_ws;       // bf16 input features
    u16* bufA = xb0 + NF;
    u16* bufB = bufA + NF;
    u16* Wswz = bufB + NF;        // 6*16384 bf16
    float* pooled = (float*)(Wswz + 6 * 16384);
    int* deg = (int*)(pooled + N_GRAPHS * DIM);
    int* ell = deg + N_NODES;     // N_NODES * ELLW

    // ---- init (tiny) + merged prep (ELL + cvt + wprep) ----
    zero_small<<<(N_NODES + 255) / 256, 256, 0, stream>>>(deg, pooled);
    prep_all<<<(N_NODES * DIM / 4 + 255) / 256, 256, 0, stream>>>(
        deg, ell, srcs, dsts, xb0, x, Wswz, convW1, convW2);

    // ---- 3 fused GIN layers ----
    const int layerBlocks = (N_NODES + 15) / 16;
    const u16* cur = xb0;
    u16* nxt = bufA;
    for (int l = 0; l < NLAYERS; ++l) {
        layer_fused<<<layerBlocks, 256, 0, stream>>>(
            nxt, cur, deg, ell,
            Wswz + (size_t)l * 16384, Wswz + (size_t)(3 + l) * 16384,
            convb1 + l * DIM, convg + l * DIM, convbt + l * DIM, convb2 + l * DIM);
        cur = nxt;
        nxt = (nxt == bufA) ? bufB : bufA;
    }

    // ---- pool (2-stage) + final MLP ----
    const int poolBlocks = ((N_NODES + 15) / 16 * 64 + 255) / 256;
    pool_partial<<<poolBlocks, 256, 0, stream>>>(pooled, cur, batch);
    tail_mlp<<<N_GRAPHS, 128, 0, stream>>>(out, pooled, mW1, mb1, mg, mbt, mW2, mb2);
}

// Round 10
// 170.931 us; speedup vs baseline: 1.1809x; 1.1809x over previous
//
#include <hip/hip_runtime.h>

#define N_NODES 50000
#define N_EDGES 600000
#define N_GRAPHS 128
#define DIM 128
#define NLAYERS 3
#define NOUT 10
#define ELLW 48      // max degree slots (deg~Binom(600k,1/50k), P(>=48)~1e-21; clamped)
#define LSTRIDE 136  // LDS row stride in bf16 elems (272B = 17*16B: aligned, 2-way max)
#define ZROW N_NODES // dummy all-zero feature row for branch-free gather padding

typedef unsigned short u16;
typedef __attribute__((ext_vector_type(8))) short bf16x8;
typedef __attribute__((ext_vector_type(4))) float f32x4;

__device__ __forceinline__ float bf2f(u16 v) {
    unsigned u = ((unsigned)v) << 16;
    return __builtin_bit_cast(float, u);
}
__device__ __forceinline__ u16 f2bf(float f) {  // round-to-nearest-even
    unsigned u = __builtin_bit_cast(unsigned, f);
    u = u + 0x7fffu + ((u >> 16) & 1u);
    return (u16)(u >> 16);
}

// ---------------------------------------------------------------------------
// tiny: zero deg + pooled (must precede prep_all's ELL atomics)
__global__ void zero_small(int* __restrict__ deg, float* __restrict__ pooled) {
    int i = blockIdx.x * blockDim.x + threadIdx.x;
    if (i < N_NODES) deg[i] = 0;
    if (i < N_GRAPHS * DIM) pooled[i] = 0.f;
}

// merged prep: ELL build + x->bf16 + W pre-swizzle + zero pad rows
__global__ void prep_all(int* __restrict__ deg, int* __restrict__ ell,
                         const int* __restrict__ srcs, const int* __restrict__ dsts,
                         u16* __restrict__ xb, u16* __restrict__ bufA, u16* __restrict__ bufB,
                         const float* __restrict__ x, u16* __restrict__ Wswz,
                         const float* __restrict__ convW1, const float* __restrict__ convW2) {
    int i = blockIdx.x * blockDim.x + threadIdx.x;
    if (i < N_EDGES) {
        int d = dsts[i];
        int slot = atomicAdd(&deg[d], 1);
        if (slot < ELLW) ell[(size_t)d * ELLW + slot] = srcs[i];
    }
    if (i < DIM) {  // zero the ZROW pad row of all three activation buffers
        xb[(size_t)ZROW * DIM + i] = 0;
        bufA[(size_t)ZROW * DIM + i] = 0;
        bufB[(size_t)ZROW * DIM + i] = 0;
    }
    if (i < 6 * 16384) {
        int j = i & 7, lane = (i >> 3) & 63, cb = (i >> 9) & 7, kc = (i >> 12) & 3, w = i >> 14;
        int k = kc * 32 + ((lane >> 4) << 3) + j;
        int c = (cb << 4) + (lane & 15);
        const float* W = (w < 3) ? (convW1 + (size_t)w * 16384) : (convW2 + (size_t)(w - 3) * 16384);
        Wswz[i] = f2bf(W[k * DIM + c]);
    }
    if (i < N_NODES * DIM / 4) {
        float4 v = ((const float4*)x)[i];
        ushort4 o;
        o.x = f2bf(v.x); o.y = f2bf(v.y); o.z = f2bf(v.z); o.w = f2bf(v.w);
        ((ushort4*)xb)[i] = o;
    }
}

// ---------------------------------------------------------------------------
// Fused GIN layer: out = relu(MLP2(relu(BN(MLP1(x + ELL-gather(x))))))
// 256 threads = 4 waves; tile 16 rows (50000 = 3125*16, no guards).
// Gather: 4 rows INTERLEAVED per wave -> 16 independent row-loads per round
// (branch-free via ZROW padding); latency rounds ~3 vs 8 serial.
__global__ __launch_bounds__(256) void layer_fused(
    u16* __restrict__ out, const u16* __restrict__ x,
    const int* __restrict__ deg, const int* __restrict__ ell,
    const u16* __restrict__ W1f, const u16* __restrict__ W2f,
    const float* __restrict__ b1, const float* __restrict__ g1,
    const float* __restrict__ bt1, const float* __restrict__ b2) {
    __shared__ u16 A[16 * LSTRIDE];  // 4352 B
    __shared__ u16 H[16 * LSTRIDE];  // 4352 B
    const int tid = threadIdx.x;
    const int wv = tid >> 6;
    const int lane = tid & 63;
    const int row0 = blockIdx.x * 16;

    // ---- phase 1: interleaved gather (wave wv -> rows wv*4..wv*4+3) ----
    const size_t coff = (size_t)lane * 2;
    {
        const int r0 = wv << 2;
        int len[4];
        const int* ep[4];
        float ax[4], ay[4];
#pragma unroll
        for (int r = 0; r < 4; ++r) {
            const int grow = row0 + r0 + r;
            len[r] = min(deg[grow], ELLW);
            ep[r] = ell + (size_t)grow * ELLW;
            ushort2 self = *(const ushort2*)(x + (size_t)grow * DIM + coff);
            ax[r] = bf2f(self.x);
            ay[r] = bf2f(self.y);
        }
        const int maxlen = max(max(len[0], len[1]), max(len[2], len[3]));
        for (int j = 0; j < maxlen; j += 4) {
            int id[4][4];
#pragma unroll
            for (int r = 0; r < 4; ++r) {
                int4 e = *(const int4*)(ep[r] + j);  // 16B-aligned (ELLW*4=192B rows)
                id[r][0] = (j + 0 < len[r]) ? e.x : ZROW;
                id[r][1] = (j + 1 < len[r]) ? e.y : ZROW;
                id[r][2] = (j + 2 < len[r]) ? e.z : ZROW;
                id[r][3] = (j + 3 < len[r]) ? e.w : ZROW;
            }
#pragma unroll
            for (int r = 0; r < 4; ++r) {
                float px = 0.f, py = 0.f;
#pragma unroll
                for (int t = 0; t < 4; ++t) {
                    ushort2 v = *(const ushort2*)(x + (size_t)id[r][t] * DIM + coff);
                    px += bf2f(v.x);
                    py += bf2f(v.y);
                }
                ax[r] += px;
                ay[r] += py;
            }
        }
#pragma unroll
        for (int r = 0; r < 4; ++r) {
            ushort2 o;
            o.x = f2bf(ax[r]);
            o.y = f2bf(ay[r]);
            *(ushort2*)&A[(r0 + r) * LSTRIDE + lane * 2] = o;
        }
    }
    __syncthreads();

    // ---- MFMA setup: wave wv owns col-blocks {2wv, 2wv+1} ----
    const float inv = rsqrtf(1.f + 1e-5f);
    const int col0 = lane & 15;
    const int rbl = (lane >> 4) << 2;  // C/D local row base
    const int fragoff = (lane & 15) * LSTRIDE + ((lane >> 4) << 3);

    // ---- phase 2: GEMM1 + BN + ReLU -> H ----
    {
        f32x4 acc[2];
        acc[0] = (f32x4){0.f, 0.f, 0.f, 0.f};
        acc[1] = (f32x4){0.f, 0.f, 0.f, 0.f};
#pragma unroll
        for (int kc = 0; kc < 4; ++kc) {
            bf16x8 a = *(const bf16x8*)&A[fragoff + kc * 32];
#pragma unroll
            for (int m = 0; m < 2; ++m) {
                const int cb = (wv << 1) + m;
                bf16x8 bb = *(const bf16x8*)(W1f + ((((kc << 3) + cb) << 6 | lane) << 3));
                acc[m] = __builtin_amdgcn_mfma_f32_16x16x32_bf16(a, bb, acc[m], 0, 0, 0);
            }
        }
#pragma unroll
        for (int m = 0; m < 2; ++m) {
            const int c = (((wv << 1) + m) << 4) + col0;
            const float bias = b1[c];
            const float sg = inv * g1[c];
            const float st = bt1[c];
#pragma unroll
            for (int q = 0; q < 4; ++q) {
                float v = (acc[m][q] + bias) * sg + st;
                H[(rbl + q) * LSTRIDE + c] = f2bf(fmaxf(v, 0.f));
            }
        }
    }
    __syncthreads();

    // ---- phase 3: GEMM2 + bias + ReLU -> A (dead; reuse as staging) ----
    {
        f32x4 acc[2];
        acc[0] = (f32x4){0.f, 0.f, 0.f, 0.f};
        acc[1] = (f32x4){0.f, 0.f, 0.f, 0.f};
#pragma unroll
        for (int kc = 0; kc < 4; ++kc) {
            bf16x8 a = *(const bf16x8*)&H[fragoff + kc * 32];
#pragma unroll
            for (int m = 0; m < 2; ++m) {
                const int cb = (wv << 1) + m;
                bf16x8 bb = *(const bf16x8*)(W2f + ((((kc << 3) + cb) << 6 | lane) << 3));
                acc[m] = __builtin_amdgcn_mfma_f32_16x16x32_bf16(a, bb, acc[m], 0, 0, 0);
            }
        }
#pragma unroll
        for (int m = 0; m < 2; ++m) {
            const int c = (((wv << 1) + m) << 4) + col0;
            const float bias = b2[c];
#pragma unroll
            for (int q = 0; q < 4; ++q) {
                float v = acc[m][q] + bias;
                A[(rbl + q) * LSTRIDE + c] = f2bf(fmaxf(v, 0.f));
            }
        }
    }
    __syncthreads();

    // ---- phase 4: coalesced copy-out (256 thr x 16B = full 16x128 tile) ----
    {
        const int r = tid >> 4;       // 0..15
        const int seg = tid & 15;     // 16B column segment
        uint4 v = *(const uint4*)&A[r * LSTRIDE + seg * 8];
        *(uint4*)(out + (size_t)(row0 + r) * DIM + seg * 8) = v;
    }
}

// ---------------------------------------------------------------------------
// pool stage 1: one wave per 16-node chunk; batch sorted -> few flushes.
__global__ __launch_bounds__(256) void pool_partial(float* __restrict__ pooled,
                                                    const u16* __restrict__ x,
                                                    const int* __restrict__ batch) {
    const int chunk = (blockIdx.x * 256 + threadIdx.x) >> 6;
    const int lane = threadIdx.x & 63;
    const int beg = chunk * 16;
    if (beg >= N_NODES) return;
    const int end = min(beg + 16, N_NODES);
    const size_t coff = (size_t)lane * 2;

    float ax = 0.f, ay = 0.f;
    int curg = batch[beg];
    for (int n = beg; n < end; ++n) {
        int g = batch[n];
        if (g != curg) {
            atomicAdd(&pooled[(size_t)curg * DIM + coff], ax);
            atomicAdd(&pooled[(size_t)curg * DIM + coff + 1], ay);
            ax = 0.f; ay = 0.f; curg = g;
        }
        ushort2 v = *(const ushort2*)(x + (size_t)n * DIM + coff);
        ax += bf2f(v.x);
        ay += bf2f(v.y);
    }
    atomicAdd(&pooled[(size_t)curg * DIM + coff], ax);
    atomicAdd(&pooled[(size_t)curg * DIM + coff + 1], ay);
}

// pool stage 2: final MLP per graph
__global__ __launch_bounds__(128) void tail_mlp(float* __restrict__ out,
                                                const float* __restrict__ pooled,
                                                const float* __restrict__ mW1,
                                                const float* __restrict__ mb1,
                                                const float* __restrict__ mg,
                                                const float* __restrict__ mbt,
                                                const float* __restrict__ mW2,
                                                const float* __restrict__ mb2) {
    const int g = blockIdx.x;
    const int c = threadIdx.x;
    __shared__ float pl[DIM];
    __shared__ float hd[DIM];
    pl[c] = pooled[(size_t)g * DIM + c];
    __syncthreads();

    float s = 0.f;
#pragma unroll 4
    for (int k = 0; k < DIM; ++k) s += pl[k] * mW1[k * DIM + c];
    const float inv = rsqrtf(1.f + 1e-5f);
    s = (s + mb1[c]) * (inv * mg[c]) + mbt[c];
    hd[c] = fmaxf(s, 0.f);
    __syncthreads();

    if (c < NOUT) {
        float o = 0.f;
#pragma unroll 4
        for (int k = 0; k < DIM; ++k) o += hd[k] * mW2[k * NOUT + c];
        out[g * NOUT + c] = o + mb2[c];
    }
}

// ---------------------------------------------------------------------------
extern "C" void kernel_launch(void* const* d_in, const int* in_sizes, int n_in,
                              void* d_out, int out_size, void* d_ws, size_t ws_size,
                              hipStream_t stream) {
    const float* x      = (const float*)d_in[0];
    const int*   ei     = (const int*)d_in[1];
    const int*   batch  = (const int*)d_in[2];
    const float* convW1 = (const float*)d_in[3];
    const float* convb1 = (const float*)d_in[4];
    const float* convg  = (const float*)d_in[5];
    const float* convbt = (const float*)d_in[6];
    const float* convW2 = (const float*)d_in[7];
    const float* convb2 = (const float*)d_in[8];
    const float* mW1    = (const float*)d_in[9];
    const float* mb1    = (const float*)d_in[10];
    const float* mg     = (const float*)d_in[11];
    const float* mbt    = (const float*)d_in[12];
    const float* mW2    = (const float*)d_in[13];
    const float* mb2    = (const float*)d_in[14];
    float* out = (float*)d_out;

    const int* srcs = ei;
    const int* dsts = ei + N_EDGES;

    // workspace layout (activation buffers have N_NODES+1 rows: ZROW pad)
    const size_t NFP = (size_t)(N_NODES + 1) * DIM;
    u16* xb0  = (u16*)d_ws;       // bf16 input features (+ zero pad row)
    u16* bufA = xb0 + NFP;
    u16* bufB = bufA + NFP;
    u16* Wswz = bufB + NFP;       // 6*16384 bf16
    float* pooled = (float*)(Wswz + 6 * 16384);
    int* deg = (int*)(pooled + N_GRAPHS * DIM);
    int* ell = deg + N_NODES;     // N_NODES * ELLW

    // ---- init (tiny) + merged prep (ELL + cvt + wprep + pad rows) ----
    zero_small<<<(N_NODES + 255) / 256, 256, 0, stream>>>(deg, pooled);
    prep_all<<<(N_NODES * DIM / 4 + 255) / 256, 256, 0, stream>>>(
        deg, ell, srcs, dsts, xb0, bufA, bufB, x, Wswz, convW1, convW2);

    // ---- 3 fused GIN layers (3125 blocks x 16 rows, exact) ----
    const int layerBlocks = N_NODES / 16;
    const u16* cur = xb0;
    u16* nxt = bufA;
    for (int l = 0; l < NLAYERS; ++l) {
        layer_fused<<<layerBlocks, 256, 0, stream>>>(
            nxt, cur, deg, ell,
            Wswz + (size_t)l * 16384, Wswz + (size_t)(3 + l) * 16384,
            convb1 + l * DIM, convg + l * DIM, convbt + l * DIM, convb2 + l * DIM);
        cur = nxt;
        nxt = (nxt == bufA) ? bufB : bufA;
    }

    // ---- pool (2-stage) + final MLP ----
    const int poolBlocks = ((N_NODES + 15) / 16 * 64 + 255) / 256;
    pool_partial<<<poolBlocks, 256, 0, stream>>>(pooled, cur, batch);
    tail_mlp<<<N_GRAPHS, 128, 0, stream>>>(out, pooled, mW1, mb1, mg, mbt, mW2, mb2);
}

// Round 11
// 154.842 us; speedup vs baseline: 1.3036x; 1.1039x over previous
//
#include <hip/hip_runtime.h>

#define N_NODES 50000
#define N_EDGES 600000
#define N_GRAPHS 128
#define DIM 128
#define NLAYERS 3
#define NOUT 10
#define ELLW 48      // max degree slots (deg~Pois(12), P(>=48)~1e-21; clamped)
#define LSTRIDE 136  // LDS row stride in bf16 elems (272B = 17*16B: aligned, 2-way max)
#define ZROW N_NODES // dummy all-zero feature row for branch-free gather padding

typedef unsigned short u16;
typedef __attribute__((ext_vector_type(8))) short bf16x8;
typedef __attribute__((ext_vector_type(4))) float f32x4;

__device__ __forceinline__ float bf2f(u16 v) {
    unsigned u = ((unsigned)v) << 16;
    return __builtin_bit_cast(float, u);
}
__device__ __forceinline__ u16 f2bf(float f) {  // round-to-nearest-even
    unsigned u = __builtin_bit_cast(unsigned, f);
    u = u + 0x7fffu + ((u >> 16) & 1u);
    return (u16)(u >> 16);
}

// ---------------------------------------------------------------------------
// tiny: zero deg + pooled (must precede prep_all's ELL atomics / layer3 pool)
__global__ void zero_small(int* __restrict__ deg, float* __restrict__ pooled) {
    int i = blockIdx.x * blockDim.x + threadIdx.x;
    if (i < N_NODES) deg[i] = 0;
    if (i < N_GRAPHS * DIM) pooled[i] = 0.f;
}

// merged prep: ELL build (u16) + x->bf16 + W pre-swizzle + zero pad rows
__global__ void prep_all(int* __restrict__ deg, u16* __restrict__ ell,
                         const int* __restrict__ srcs, const int* __restrict__ dsts,
                         u16* __restrict__ xb, u16* __restrict__ bufA, u16* __restrict__ bufB,
                         const float* __restrict__ x, u16* __restrict__ Wswz,
                         const float* __restrict__ convW1, const float* __restrict__ convW2) {
    int i = blockIdx.x * blockDim.x + threadIdx.x;
    if (i < N_EDGES) {
        int d = dsts[i];
        int slot = atomicAdd(&deg[d], 1);
        if (slot < ELLW) ell[(size_t)d * ELLW + slot] = (u16)srcs[i];
    }
    if (i < DIM) {  // zero the ZROW pad row of all three activation buffers
        xb[(size_t)ZROW * DIM + i] = 0;
        bufA[(size_t)ZROW * DIM + i] = 0;
        bufB[(size_t)ZROW * DIM + i] = 0;
    }
    if (i < 6 * 16384) {
        int j = i & 7, lane = (i >> 3) & 63, cb = (i >> 9) & 7, kc = (i >> 12) & 3, w = i >> 14;
        int k = kc * 32 + ((lane >> 4) << 3) + j;
        int c = (cb << 4) + (lane & 15);
        const float* W = (w < 3) ? (convW1 + (size_t)w * 16384) : (convW2 + (size_t)(w - 3) * 16384);
        Wswz[i] = f2bf(W[k * DIM + c]);
    }
    if (i < N_NODES * DIM / 4) {
        float4 v = ((const float4*)x)[i];
        ushort4 o;
        o.x = f2bf(v.x); o.y = f2bf(v.y); o.z = f2bf(v.z); o.w = f2bf(v.w);
        ((ushort4*)xb)[i] = o;
    }
}

// ---------------------------------------------------------------------------
// Fused GIN layer: out = relu(MLP2(relu(BN(MLP1(x + ELL-gather(x))))))
// 256 threads = 4 waves; tile 16 rows (50000 = 3125*16, no guards).
// Gather: 4 rows interleaved/wave -> 16 independent row-loads per round.
// POOL=1 (last layer): skip global store; per-graph column-sum the LDS tile
// into pooled[] via atomicAdd (batch sorted -> runs; flush on change).
template <int POOL>
__global__ __launch_bounds__(256) void layer_fused(
    u16* __restrict__ out, const u16* __restrict__ x,
    const int* __restrict__ deg, const u16* __restrict__ ell,
    const u16* __restrict__ W1f, const u16* __restrict__ W2f,
    const float* __restrict__ b1, const float* __restrict__ g1,
    const float* __restrict__ bt1, const float* __restrict__ b2,
    const int* __restrict__ batch, float* __restrict__ pooled) {
    __shared__ u16 A[16 * LSTRIDE];  // 4352 B
    __shared__ u16 H[16 * LSTRIDE];  // 4352 B
    __shared__ int gb[16];
    const int tid = threadIdx.x;
    const int wv = tid >> 6;
    const int lane = tid & 63;
    const int row0 = blockIdx.x * 16;

    if (POOL && tid < 16) gb[tid] = batch[row0 + tid];

    // ---- phase 1: interleaved gather (wave wv -> rows wv*4..wv*4+3) ----
    const size_t coff = (size_t)lane * 2;
    {
        const int r0 = wv << 2;
        int len[4];
        const u16* ep[4];
        float ax[4], ay[4];
#pragma unroll
        for (int r = 0; r < 4; ++r) {
            const int grow = row0 + r0 + r;
            len[r] = min(deg[grow], ELLW);
            ep[r] = ell + (size_t)grow * ELLW;
            ushort2 self = *(const ushort2*)(x + (size_t)grow * DIM + coff);
            ax[r] = bf2f(self.x);
            ay[r] = bf2f(self.y);
        }
        const int maxlen = max(max(len[0], len[1]), max(len[2], len[3]));
        for (int j = 0; j < maxlen; j += 4) {
            int id[4][4];
#pragma unroll
            for (int r = 0; r < 4; ++r) {
                ushort4 e = *(const ushort4*)(ep[r] + j);  // 8B-aligned (96B rows)
                id[r][0] = (j + 0 < len[r]) ? (int)e.x : ZROW;
                id[r][1] = (j + 1 < len[r]) ? (int)e.y : ZROW;
                id[r][2] = (j + 2 < len[r]) ? (int)e.z : ZROW;
                id[r][3] = (j + 3 < len[r]) ? (int)e.w : ZROW;
            }
#pragma unroll
            for (int r = 0; r < 4; ++r) {
                float px = 0.f, py = 0.f;
#pragma unroll
                for (int t = 0; t < 4; ++t) {
                    ushort2 v = *(const ushort2*)(x + (size_t)id[r][t] * DIM + coff);
                    px += bf2f(v.x);
                    py += bf2f(v.y);
                }
                ax[r] += px;
                ay[r] += py;
            }
        }
#pragma unroll
        for (int r = 0; r < 4; ++r) {
            ushort2 o;
            o.x = f2bf(ax[r]);
            o.y = f2bf(ay[r]);
            *(ushort2*)&A[(r0 + r) * LSTRIDE + lane * 2] = o;
        }
    }
    __syncthreads();

    // ---- MFMA setup: wave wv owns col-blocks {2wv, 2wv+1} ----
    const float inv = rsqrtf(1.f + 1e-5f);
    const int col0 = lane & 15;
    const int rbl = (lane >> 4) << 2;  // C/D local row base
    const int fragoff = (lane & 15) * LSTRIDE + ((lane >> 4) << 3);

    // ---- phase 2: GEMM1 + BN + ReLU -> H ----
    {
        f32x4 acc[2];
        acc[0] = (f32x4){0.f, 0.f, 0.f, 0.f};
        acc[1] = (f32x4){0.f, 0.f, 0.f, 0.f};
#pragma unroll
        for (int kc = 0; kc < 4; ++kc) {
            bf16x8 a = *(const bf16x8*)&A[fragoff + kc * 32];
#pragma unroll
            for (int m = 0; m < 2; ++m) {
                const int cb = (wv << 1) + m;
                bf16x8 bb = *(const bf16x8*)(W1f + ((((kc << 3) + cb) << 6 | lane) << 3));
                acc[m] = __builtin_amdgcn_mfma_f32_16x16x32_bf16(a, bb, acc[m], 0, 0, 0);
            }
        }
#pragma unroll
        for (int m = 0; m < 2; ++m) {
            const int c = (((wv << 1) + m) << 4) + col0;
            const float bias = b1[c];
            const float sg = inv * g1[c];
            const float st = bt1[c];
#pragma unroll
            for (int q = 0; q < 4; ++q) {
                float v = (acc[m][q] + bias) * sg + st;
                H[(rbl + q) * LSTRIDE + c] = f2bf(fmaxf(v, 0.f));
            }
        }
    }
    __syncthreads();

    // ---- phase 3: GEMM2 + bias + ReLU -> A (dead; reuse as staging) ----
    {
        f32x4 acc[2];
        acc[0] = (f32x4){0.f, 0.f, 0.f, 0.f};
        acc[1] = (f32x4){0.f, 0.f, 0.f, 0.f};
#pragma unroll
        for (int kc = 0; kc < 4; ++kc) {
            bf16x8 a = *(const bf16x8*)&H[fragoff + kc * 32];
#pragma unroll
            for (int m = 0; m < 2; ++m) {
                const int cb = (wv << 1) + m;
                bf16x8 bb = *(const bf16x8*)(W2f + ((((kc << 3) + cb) << 6 | lane) << 3));
                acc[m] = __builtin_amdgcn_mfma_f32_16x16x32_bf16(a, bb, acc[m], 0, 0, 0);
            }
        }
#pragma unroll
        for (int m = 0; m < 2; ++m) {
            const int c = (((wv << 1) + m) << 4) + col0;
            const float bias = b2[c];
#pragma unroll
            for (int q = 0; q < 4; ++q) {
                float v = acc[m][q] + bias;
                A[(rbl + q) * LSTRIDE + c] = f2bf(fmaxf(v, 0.f));
            }
        }
    }
    __syncthreads();

    if (!POOL) {
        // ---- phase 4: coalesced copy-out (256 thr x 16B = full tile) ----
        const int r = tid >> 4;       // 0..15
        const int seg = tid & 15;     // 16B column segment
        uint4 v = *(const uint4*)&A[r * LSTRIDE + seg * 8];
        *(uint4*)(out + (size_t)(row0 + r) * DIM + seg * 8) = v;
    } else {
        // ---- phase 4': per-graph column sums -> pooled (atomicAdd) ----
        const int c = tid & 127;
        const int rbeg = (tid >> 7) << 3;  // 0 or 8
        float acc = 0.f;
        int curg = gb[rbeg];
#pragma unroll
        for (int r = 0; r < 8; ++r) {
            const int g = gb[rbeg + r];
            if (g != curg) {
                atomicAdd(&pooled[(size_t)curg * DIM + c], acc);
                acc = 0.f;
                curg = g;
            }
            acc += bf2f(A[(rbeg + r) * LSTRIDE + c]);
        }
        atomicAdd(&pooled[(size_t)curg * DIM + c], acc);
    }
}

// ---------------------------------------------------------------------------
// final MLP per graph
__global__ __launch_bounds__(128) void tail_mlp(float* __restrict__ out,
                                                const float* __restrict__ pooled,
                                                const float* __restrict__ mW1,
                                                const float* __restrict__ mb1,
                                                const float* __restrict__ mg,
                                                const float* __restrict__ mbt,
                                                const float* __restrict__ mW2,
                                                const float* __restrict__ mb2) {
    const int g = blockIdx.x;
    const int c = threadIdx.x;
    __shared__ float pl[DIM];
    __shared__ float hd[DIM];
    pl[c] = pooled[(size_t)g * DIM + c];
    __syncthreads();

    float s = 0.f;
#pragma unroll 4
    for (int k = 0; k < DIM; ++k) s += pl[k] * mW1[k * DIM + c];
    const float inv = rsqrtf(1.f + 1e-5f);
    s = (s + mb1[c]) * (inv * mg[c]) + mbt[c];
    hd[c] = fmaxf(s, 0.f);
    __syncthreads();

    if (c < NOUT) {
        float o = 0.f;
#pragma unroll 4
        for (int k = 0; k < DIM; ++k) o += hd[k] * mW2[k * NOUT + c];
        out[g * NOUT + c] = o + mb2[c];
    }
}

// ---------------------------------------------------------------------------
extern "C" void kernel_launch(void* const* d_in, const int* in_sizes, int n_in,
                              void* d_out, int out_size, void* d_ws, size_t ws_size,
                              hipStream_t stream) {
    const float* x      = (const float*)d_in[0];
    const int*   ei     = (const int*)d_in[1];
    const int*   batch  = (const int*)d_in[2];
    const float* convW1 = (const float*)d_in[3];
    const float* convb1 = (const float*)d_in[4];
    const float* convg  = (const float*)d_in[5];
    const float* convbt = (const float*)d_in[6];
    const float* convW2 = (const float*)d_in[7];
    const float* convb2 = (const float*)d_in[8];
    const float* mW1    = (const float*)d_in[9];
    const float* mb1    = (const float*)d_in[10];
    const float* mg     = (const float*)d_in[11];
    const float* mbt    = (const float*)d_in[12];
    const float* mW2    = (const float*)d_in[13];
    const float* mb2    = (const float*)d_in[14];
    float* out = (float*)d_out;

    const int* srcs = ei;
    const int* dsts = ei + N_EDGES;

    // workspace layout (activation buffers have N_NODES+1 rows: ZROW pad)
    const size_t NFP = (size_t)(N_NODES + 1) * DIM;
    u16* xb0  = (u16*)d_ws;       // bf16 input features (+ zero pad row)
    u16* bufA = xb0 + NFP;
    u16* bufB = bufA + NFP;
    u16* Wswz = bufB + NFP;       // 6*16384 bf16
    float* pooled = (float*)(Wswz + 6 * 16384);
    int* deg = (int*)(pooled + N_GRAPHS * DIM);
    u16* ell = (u16*)(deg + N_NODES);  // N_NODES * ELLW u16

    // ---- init (tiny) + merged prep (ELL + cvt + wprep + pad rows) ----
    zero_small<<<(N_NODES + 255) / 256, 256, 0, stream>>>(deg, pooled);
    prep_all<<<(N_NODES * DIM / 4 + 255) / 256, 256, 0, stream>>>(
        deg, ell, srcs, dsts, xb0, bufA, bufB, x, Wswz, convW1, convW2);

    // ---- 3 fused GIN layers (3125 blocks x 16 rows, exact) ----
    const int layerBlocks = N_NODES / 16;
    layer_fused<0><<<layerBlocks, 256, 0, stream>>>(
        bufA, xb0, deg, ell, Wswz, Wswz + (size_t)3 * 16384,
        convb1, convg, convbt, convb2, batch, pooled);
    layer_fused<0><<<layerBlocks, 256, 0, stream>>>(
        bufB, bufA, deg, ell, Wswz + (size_t)1 * 16384, Wswz + (size_t)4 * 16384,
        convb1 + DIM, convg + DIM, convbt + DIM, convb2 + DIM, batch, pooled);
    layer_fused<1><<<layerBlocks, 256, 0, stream>>>(
        bufA /*unused*/, bufB, deg, ell, Wswz + (size_t)2 * 16384, Wswz + (size_t)5 * 16384,
        convb1 + 2 * DIM, convg + 2 * DIM, convbt + 2 * DIM, convb2 + 2 * DIM, batch, pooled);

    // ---- final MLP ----
    tail_mlp<<<N_GRAPHS, 128, 0, stream>>>(out, pooled, mW1, mb1, mg, mbt, mW2, mb2);
}